// Round 1
// baseline (10225.125 us; speedup 1.0000x reference)
//
#include <hip/hip_runtime.h>
#include <math.h>

// ===========================================================================
// ImplicitMap fExtractor: 12-layer 1x1-conv MLP with gradient chain.
// State per point: 4 planes [x, g0, g1, g2], each length C (<=960).
// Per layer (mid): Z_p = S_p @ W^T  (4 GEMMs sharing W);
//   gate = sigmoid(100*Z_x); x' = softplus(100*Z_x)/100; g_i' = gate * Z_gi.
// One fused kernel per layer: each workgroup owns a 64x64 (m,o) tile for all
// 4 planes so the gate coupling stays in registers.
// fp32 vector-ALU GEMM (no fp32 MFMA on CDNA4). Compute-bound ~157 TF peak.
// ===========================================================================

#define BM 64
#define BN 64
#define BK 32
#define LDSM 68   // BM + 4 pad: 2-way-max LDS bank conflicts (verified pattern)

template<int P>   // P=1: first layer (x only, g seeded from W[:, :3]); P=4: mid
__global__ __launch_bounds__(256)
void layer_gemm(const float* __restrict__ Sin, size_t psIn, int ldIn,
                float* __restrict__ Sout, size_t psOut, int ldOut,
                const float* __restrict__ W, const float* __restrict__ bias,
                int Cin, int Cout)
{
    constexpr bool FIRST = (P == 1);
    __shared__ __align__(16) float Xs[P][BK][LDSM];
    __shared__ __align__(16) float Ws[BK][LDSM];

    const int tid = threadIdx.x;
    const int m0 = blockIdx.x * BM;
    const int o0 = blockIdx.y * BN;

    const int r  = tid >> 2;   // 0..63 : row being staged
    const int q  = tid & 3;    // 0..3  : k-quad being staged
    const int tm = tid & 15;   // m-quad of this thread's 4x4 outputs
    const int to = tid >> 4;   // o-quad

    float acc[P][4][4];
    #pragma unroll
    for (int p = 0; p < P; ++p)
        #pragma unroll
        for (int i = 0; i < 4; ++i)
            #pragma unroll
            for (int j = 0; j < 4; ++j)
                acc[p][i][j] = 0.f;

    const bool alignedW = ((Cin & 3) == 0);     // W rows 16B-aligned iff Cin%4==0
    const bool wRowOk   = (o0 + r) < Cout;
    const float* wRow = W + (size_t)(o0 + r) * Cin;

    for (int kk = 0; kk < Cin; kk += BK) {
        // ---- stage state planes (transpose to k-major) ----
        #pragma unroll
        for (int p = 0; p < P; ++p) {
            const float* srcRow = Sin + (size_t)p * psIn + (size_t)(m0 + r) * ldIn;
            #pragma unroll
            for (int pass = 0; pass < 2; ++pass) {
                const int kl = pass * 16 + q * 4;
                const int c0 = kk + kl;
                float v0, v1, v2, v3;
                if (!FIRST && (c0 + 3 < Cin)) {   // planes are ld%4 padded+aligned
                    const float4 vv = *reinterpret_cast<const float4*>(srcRow + c0);
                    v0 = vv.x; v1 = vv.y; v2 = vv.z; v3 = vv.w;
                } else {                           // tail / unaligned (layer-1 ld=259)
                    v0 = (c0 + 0 < Cin) ? srcRow[c0 + 0] : 0.f;
                    v1 = (c0 + 1 < Cin) ? srcRow[c0 + 1] : 0.f;
                    v2 = (c0 + 2 < Cin) ? srcRow[c0 + 2] : 0.f;
                    v3 = (c0 + 3 < Cin) ? srcRow[c0 + 3] : 0.f;
                }
                Xs[p][kl + 0][r] = v0;
                Xs[p][kl + 1][r] = v1;
                Xs[p][kl + 2][r] = v2;
                Xs[p][kl + 3][r] = v3;
            }
        }
        // ---- stage weight tile (transpose to k-major) ----
        #pragma unroll
        for (int pass = 0; pass < 2; ++pass) {
            const int kl = pass * 16 + q * 4;
            const int c0 = kk + kl;
            float v0 = 0.f, v1 = 0.f, v2 = 0.f, v3 = 0.f;
            if (wRowOk) {
                if (alignedW && (c0 + 3 < Cin)) {
                    const float4 vv = *reinterpret_cast<const float4*>(wRow + c0);
                    v0 = vv.x; v1 = vv.y; v2 = vv.z; v3 = vv.w;
                } else {
                    v0 = (c0 + 0 < Cin) ? wRow[c0 + 0] : 0.f;
                    v1 = (c0 + 1 < Cin) ? wRow[c0 + 1] : 0.f;
                    v2 = (c0 + 2 < Cin) ? wRow[c0 + 2] : 0.f;
                    v3 = (c0 + 3 < Cin) ? wRow[c0 + 3] : 0.f;
                }
            }
            Ws[kl + 0][r] = v0;
            Ws[kl + 1][r] = v1;
            Ws[kl + 2][r] = v2;
            Ws[kl + 3][r] = v3;
        }
        __syncthreads();

        // ---- inner product: 64 (P=4) FMAs per k per thread ----
        #pragma unroll 4
        for (int k = 0; k < BK; ++k) {
            const float4 wv = *reinterpret_cast<const float4*>(&Ws[k][to * 4]);
            #pragma unroll
            for (int p = 0; p < P; ++p) {
                const float4 xv = *reinterpret_cast<const float4*>(&Xs[p][k][tm * 4]);
                acc[p][0][0] += xv.x * wv.x; acc[p][0][1] += xv.x * wv.y;
                acc[p][0][2] += xv.x * wv.z; acc[p][0][3] += xv.x * wv.w;
                acc[p][1][0] += xv.y * wv.x; acc[p][1][1] += xv.y * wv.y;
                acc[p][1][2] += xv.y * wv.z; acc[p][1][3] += xv.y * wv.w;
                acc[p][2][0] += xv.z * wv.x; acc[p][2][1] += xv.z * wv.y;
                acc[p][2][2] += xv.z * wv.z; acc[p][2][3] += xv.z * wv.w;
                acc[p][3][0] += xv.w * wv.x; acc[p][3][1] += xv.w * wv.y;
                acc[p][3][2] += xv.w * wv.z; acc[p][3][3] += xv.w * wv.w;
            }
        }
        __syncthreads();
    }

    // ---- epilogue: bias, gate, softplus, gradient gating ----
    #pragma unroll
    for (int j = 0; j < 4; ++j) {
        const int o = o0 + to * 4 + j;
        if (o >= Cout) continue;
        const float bo = bias[o];
        float w0 = 0.f, w1 = 0.f, w2 = 0.f;
        if (FIRST) {
            w0 = W[(size_t)o * Cin + 0];
            w1 = W[(size_t)o * Cin + 1];
            w2 = W[(size_t)o * Cin + 2];
        }
        #pragma unroll
        for (int i = 0; i < 4; ++i) {
            const int m = m0 + tm * 4 + i;
            const float z = acc[0][i][j] + bo;
            const float gate = 1.f / (1.f + expf(-100.f * z));
            const float sp = fmaxf(z, 0.f) + 0.01f * log1pf(expf(-100.f * fabsf(z)));
            float* outP = Sout + (size_t)m * ldOut + o;
            outP[0] = sp;
            if (FIRST) {
                outP[psOut]     = gate * w0;
                outP[2 * psOut] = gate * w1;
                outP[3 * psOut] = gate * w2;
            } else {
                outP[psOut]     = gate * acc[1][i][j];
                outP[2 * psOut] = gate * acc[2][i][j];
                outP[3 * psOut] = gate * acc[3][i][j];
            }
        }
    }
}

// Final 896->1 layer: z = x.W + b (no activation), g = W @ g (no gate).
__global__ __launch_bounds__(256)
void final_layer(const float* __restrict__ Sin, size_t ps, int ld,
                 const float* __restrict__ W, const float* __restrict__ bias,
                 float* __restrict__ out1, float* __restrict__ out2,
                 int Cin, int mBase)
{
    const int lane = threadIdx.x & 63;
    const int wv   = threadIdx.x >> 6;
    const int m = blockIdx.x * 4 + wv;
    const float* row = Sin + (size_t)m * ld;
    float s0 = 0.f, s1 = 0.f, s2 = 0.f, s3 = 0.f;
    for (int c = lane; c < Cin; c += 64) {
        const float w = W[c];
        s0 += row[c] * w;
        s1 += row[ps + c] * w;
        s2 += row[2 * ps + c] * w;
        s3 += row[3 * ps + c] * w;
    }
    #pragma unroll
    for (int off = 32; off > 0; off >>= 1) {
        s0 += __shfl_xor(s0, off);
        s1 += __shfl_xor(s1, off);
        s2 += __shfl_xor(s2, off);
        s3 += __shfl_xor(s3, off);
    }
    if (lane == 0) {
        out1[mBase + m] = s0 + bias[0];
        float* g = out2 + (size_t)(mBase + m) * 3;
        g[0] = s1; g[1] = s2; g[2] = s3;
    }
}

// input_con = concat(input[m, :3], latent[b, :]) -> also output #3, then reused
// as the layer-1 GEMM input.
__global__ void write_input_con(const float* __restrict__ input,
                                const float* __restrict__ latent,
                                float* __restrict__ out3, int N)
{
    const int m = blockIdx.x;
    const int b = m / N;
    float* dst = out3 + (size_t)m * 259;
    const float* inRow = input + (size_t)m * 3;
    const float* lat = latent + (size_t)b * 256;
    for (int c = threadIdx.x; c < 259; c += blockDim.x) {
        dst[c] = (c < 3) ? inRow[c] : lat[c - 3];
    }
}

extern "C" void kernel_launch(void* const* d_in, const int* in_sizes, int n_in,
                              void* d_out, int out_size, void* d_ws, size_t ws_size,
                              hipStream_t stream)
{
    static const int CIN [12] = {259,515,512,512,576,576,768,768,768,960,960,896};
    static const int COUT[12] = {515,512,512,576,576,768,768,768,960,960,896,1};

    const float* input  = (const float*)d_in[0];
    const float* latent = (const float*)d_in[1];
    auto Wp = [&](int i){ return (const float*)d_in[2 + 2 * i]; };
    auto Bp = [&](int i){ return (const float*)d_in[3 + 2 * i]; };

    const int Bn = in_sizes[1] / 256;          // batch (2)
    const int Nn = in_sizes[0] / (3 * Bn);     // points per batch (8192)
    const int M  = Bn * Nn;                    // 16384

    float* out1 = (float*)d_out;               // (B,1,N) == flat m
    float* out2 = out1 + M;                    // (B,N,1,3)
    float* out3 = out2 + (size_t)M * 3;        // input_con (B,N,259)

    write_input_con<<<M, 256, 0, stream>>>(input, latent, out3, Nn);

    // Chunk points so two 4-plane ping-pong state buffers fit in ws.
    const size_t perPoint = 2ull * 4ull * 960ull * 4ull;   // 30720 B/point
    long long pc = (long long)(ws_size / perPoint);
    int Pc = (int)(pc & ~63LL);
    if (Pc < 64) Pc = 64;
    if (Pc > M)  Pc = M;
    const size_t planeStride = (size_t)Pc * 960;           // elements
    float* bufA = (float*)d_ws;
    float* bufB = bufA + 4 * planeStride;

    auto pad4 = [](int c){ return (c + 3) & ~3; };

    for (int cm0 = 0; cm0 < M; cm0 += Pc) {
        const int Mc = (M - cm0 < Pc) ? (M - cm0) : Pc;

        {   // layer 1: reads input_con (ld=259, unaligned -> scalar staging)
            dim3 g(Mc / BM, (COUT[0] + BN - 1) / BN);
            layer_gemm<1><<<g, 256, 0, stream>>>(
                out3 + (size_t)cm0 * 259, 0, 259,
                bufA, planeStride, pad4(COUT[0]),
                Wp(0), Bp(0), CIN[0], COUT[0]);
        }
        float* src = bufA;
        float* dst = bufB;
        for (int l = 1; l <= 10; ++l) {   // 10 fused ResNeXt blocks
            dim3 g(Mc / BM, (COUT[l] + BN - 1) / BN);
            layer_gemm<4><<<g, 256, 0, stream>>>(
                src, planeStride, pad4(CIN[l]),
                dst, planeStride, pad4(COUT[l]),
                Wp(l), Bp(l), CIN[l], COUT[l]);
            float* t = src; src = dst; dst = t;
        }
        // layer 12: 896 -> 1, no activation, no gate
        final_layer<<<Mc / 4, 256, 0, stream>>>(
            src, planeStride, pad4(CIN[11]),
            Wp(11), Bp(11), out1, out2, CIN[11], cm0);
    }
}

// Round 2
// 3161.940 us; speedup vs baseline: 3.2338x; 3.2338x over previous
//
#include <hip/hip_runtime.h>
#include <math.h>

// ===========================================================================
// ImplicitMap fExtractor on MFMA (fp16 split scheme).
// State per point = 5 fp16 planes: [x_hi, x_lo, g1, g2, g3].
//   x carried as exact fp16 hi+lo pair -> 3-pass MFMA == fp32-accurate z
//   (gate = sigmoid(100 z) is the precision-critical path).
//   g planes single-pass fp16 (errors propagate linearly, no gate blowup).
// Weights pre-split to zero-padded fp16 hi/lo in ws once per launch.
// GEMM kernel: 64m x 128o x 4planes per 256-thread block, 32x32x16 f16 MFMA,
// K-outer-major LDS tiles [kq][row][8] -> conflict-free ds_read_b128 and
// linear global_load_lds staging. 2-phase double-buffered K loop.
// ===========================================================================

typedef unsigned short u16;
typedef _Float16 f16;
typedef f16   f16x8  __attribute__((ext_vector_type(8)));
typedef float f32x16 __attribute__((ext_vector_type(16)));

__device__ __forceinline__ u16   f2h(float x){ return __builtin_bit_cast(u16, (f16)x); }
__device__ __forceinline__ float h2f(u16 b){ return (float)__builtin_bit_cast(f16, b); }

__device__ __forceinline__ void glld16(const void* g, void* l){
  __builtin_amdgcn_global_load_lds(
      (const __attribute__((address_space(1))) unsigned*)g,
      (__attribute__((address_space(3))) unsigned*)l, 16, 0, 0);
}

// NP = input planes staged: 2 for layer 1 (x hi/lo), 5 for mid layers.
template<int NP>
__global__ __launch_bounds__(256, 2)
void fused_layer(const u16* __restrict__ Sin, long long psIn, int kpad,
                 u16* __restrict__ Sout, long long psOut, int opitch,
                 const u16* __restrict__ Wh, const u16* __restrict__ Wl,
                 const float* __restrict__ bias, const float* __restrict__ Wfirst,
                 int cout, int cinFirst)
{
  constexpr bool FIRST = (NP == 2);
  // K-outer-major: [buf][tile][kq(8-elem block)][row][8]; 16B cell per (kq,row)
  __shared__ u16 As[2][NP][4][64][8];
  __shared__ u16 Bs[2][2][4][128][8];

  const int tid   = threadIdx.x;
  const int w     = tid >> 6;     // wave id: stages kq-block w of every tile
  const int lane  = tid & 63;
  const int lrow  = lane & 31;
  const int lhalf = lane >> 5;
  const int mh    = w >> 1;       // wave's m-half (32 rows)
  const int oh    = w & 1;        // wave's o-half (64 cols)
  const int m0    = blockIdx.x * 64;
  const int o0    = blockIdx.y * 128;

  f32x16 zinit = {};
  f32x16 accx[2];
  f32x16 accg[FIRST ? 1 : 3][2];
  accx[0] = zinit; accx[1] = zinit;
  if constexpr (!FIRST){
    #pragma unroll
    for (int j = 0; j < 3; ++j){ accg[j][0] = zinit; accg[j][1] = zinit; }
  }

  // per-lane global sources (lane -> LDS base + lane*16 by glld semantics)
  const u16* aSrc[NP];
  #pragma unroll
  for (int p = 0; p < NP; ++p)
    aSrc[p] = Sin + (long long)p * psIn + (long long)(m0 + lane) * kpad + w * 8;
  const u16* bSrc[2][2];
  #pragma unroll
  for (int h = 0; h < 2; ++h){
    const u16* Wx = h ? Wl : Wh;
    #pragma unroll
    for (int hf = 0; hf < 2; ++hf)
      bSrc[h][hf] = Wx + (long long)(o0 + hf*64 + lane) * kpad + w * 8;
  }

  auto stage = [&](int cur, int kk){
    #pragma unroll
    for (int p = 0; p < NP; ++p)
      glld16(aSrc[p] + kk, &As[cur][p][w][0][0]);
    #pragma unroll
    for (int h = 0; h < 2; ++h)
      #pragma unroll
      for (int hf = 0; hf < 2; ++hf)
        glld16(bSrc[h][hf] + kk, &Bs[cur][h][w][hf*64][0]);
  };

  auto compute = [&](int cur){
    #pragma unroll
    for (int s = 0; s < 2; ++s){
      const int kq = s*2 + lhalf;        // A/B frag: k = 8*(lane>>5)+e
      f16x8 a[NP];
      #pragma unroll
      for (int p = 0; p < NP; ++p)
        a[p] = *(const f16x8*)&As[cur][p][kq][mh*32 + lrow][0];
      #pragma unroll
      for (int f = 0; f < 2; ++f){
        const int oc = oh*64 + f*32 + lrow;
        f16x8 bh = *(const f16x8*)&Bs[cur][0][kq][oc][0];
        f16x8 bl = *(const f16x8*)&Bs[cur][1][kq][oc][0];
        // x plane: 3-pass split (xh*Wh + xl*Wh + xh*Wl), ~fp32 accurate
        accx[f] = __builtin_amdgcn_mfma_f32_32x32x16_f16(a[0], bh, accx[f], 0,0,0);
        accx[f] = __builtin_amdgcn_mfma_f32_32x32x16_f16(a[1], bh, accx[f], 0,0,0);
        accx[f] = __builtin_amdgcn_mfma_f32_32x32x16_f16(a[0], bl, accx[f], 0,0,0);
        if constexpr (!FIRST){
          #pragma unroll
          for (int j = 0; j < 3; ++j)   // g planes: single pass
            accg[j][f] = __builtin_amdgcn_mfma_f32_32x32x16_f16(a[2+j], bh, accg[j][f], 0,0,0);
        }
      }
    }
  };

  const int nk = kpad >> 5;
  stage(0, 0);
  __syncthreads();
  int cur = 0;
  for (int t = 1; t < nk; ++t){
    stage(cur ^ 1, t * 32);   // issue next tile's loads before compute (T3 min)
    compute(cur);
    __syncthreads();          // drains vmcnt(0): next buffer landed
    cur ^= 1;
  }
  compute(cur);

  // ---- epilogue: D layout col=lane&31, row=(r&3)+8*(r>>2)+4*(lane>>5) ----
  const int mb = m0 + mh*32;
  #pragma unroll
  for (int f = 0; f < 2; ++f){
    const int o = o0 + oh*64 + f*32 + lrow;
    const float bo = (o < cout) ? bias[o] : 0.f;
    float w0 = 0.f, w1 = 0.f, w2 = 0.f;
    if constexpr (FIRST){
      if (o < cout){
        w0 = Wfirst[(long long)o*cinFirst + 0];
        w1 = Wfirst[(long long)o*cinFirst + 1];
        w2 = Wfirst[(long long)o*cinFirst + 2];
      }
    }
    #pragma unroll
    for (int r = 0; r < 16; ++r){
      const int m = mb + (r & 3) + ((r >> 2) << 3) + (lhalf << 2);
      const float z    = accx[f][r] + bo;
      const float gate = 1.f / (1.f + expf(-100.f * z));
      const float sp   = fmaxf(z, 0.f) + 0.01f * log1pf(expf(-100.f * fabsf(z)));
      const long long idx = (long long)m * opitch + o;
      const u16 xh = f2h(sp);
      Sout[idx]          = xh;
      Sout[psOut + idx]  = f2h(sp - h2f(xh));
      if constexpr (FIRST){
        Sout[2*psOut + idx] = f2h(gate * w0);
        Sout[3*psOut + idx] = f2h(gate * w1);
        Sout[4*psOut + idx] = f2h(gate * w2);
      } else {
        Sout[2*psOut + idx] = f2h(gate * accg[0][f][r]);
        Sout[3*psOut + idx] = f2h(gate * accg[1][f][r]);
        Sout[4*psOut + idx] = f2h(gate * accg[2][f][r]);
      }
    }
  }
}

// Final 896->1: z (no act) -> out1; g = W@g (no gate) -> out2.
__global__ __launch_bounds__(256)
void final_layer(const u16* __restrict__ Sin, long long ps, int kpad,
                 const float* __restrict__ W, const float* __restrict__ bias,
                 float* __restrict__ out1, float* __restrict__ out2,
                 int cin, int mBase)
{
  const int lane = threadIdx.x & 63;
  const int wv   = threadIdx.x >> 6;
  const int m = blockIdx.x * 4 + wv;
  const u16* row = Sin + (long long)m * kpad;
  float s0=0.f, s1=0.f, s2=0.f, s3=0.f;
  for (int c = lane; c < cin; c += 64){
    const float w = W[c];
    s0 += (h2f(row[c]) + h2f(row[ps + c])) * w;
    s1 += h2f(row[2*ps + c]) * w;
    s2 += h2f(row[3*ps + c]) * w;
    s3 += h2f(row[4*ps + c]) * w;
  }
  #pragma unroll
  for (int off = 32; off > 0; off >>= 1){
    s0 += __shfl_xor(s0, off); s1 += __shfl_xor(s1, off);
    s2 += __shfl_xor(s2, off); s3 += __shfl_xor(s3, off);
  }
  if (lane == 0){
    out1[mBase + m] = s0 + bias[0];
    float* g = out2 + (long long)(mBase + m) * 3;
    g[0] = s1; g[1] = s2; g[2] = s3;
  }
}

// out3 = input_con (fp32), plus padded fp16 hi/lo copy for the layer-1 GEMM.
__global__ void prep_input(const float* __restrict__ input,
                           const float* __restrict__ latent,
                           float* __restrict__ out3,
                           u16* __restrict__ x0, long long psX0, int N)
{
  const int m = blockIdx.x;
  const int b = m / N;
  const int c = threadIdx.x;
  if (c >= 288) return;
  float v = 0.f;
  if (c < 3) v = input[(long long)m*3 + c];
  else if (c < 259) v = latent[(long long)b*256 + (c - 3)];
  if (c < 259) out3[(long long)m*259 + c] = v;
  const u16 h = f2h(v);
  x0[(long long)m*288 + c]        = h;
  x0[psX0 + (long long)m*288 + c] = f2h(v - h2f(h));
}

// fp32 W -> zero-padded fp16 hi/lo.
__global__ void split_w(const float* __restrict__ W, u16* __restrict__ wh,
                        u16* __restrict__ wl, int cout, int cin, int kpad, int total)
{
  const int idx = blockIdx.x * 256 + threadIdx.x;
  if (idx >= total) return;
  const int o = idx / kpad, c = idx % kpad;
  const float v = (o < cout && c < cin) ? W[(long long)o*cin + c] : 0.f;
  const u16 h = f2h(v);
  wh[idx] = h;
  wl[idx] = f2h(v - h2f(h));
}

extern "C" void kernel_launch(void* const* d_in, const int* in_sizes, int n_in,
                              void* d_out, int out_size, void* d_ws, size_t ws_size,
                              hipStream_t stream)
{
  static const int CIN [12] = {259,515,512,512,576,576,768,768,768,960,960,896};
  static const int COUT[12] = {515,512,512,576,576,768,768,768,960,960,896,1};
  int OPAD[11], KPAD[12];
  KPAD[0] = 288;
  for (int i = 0; i < 11; ++i){
    OPAD[i] = ((COUT[i] + 127) / 128) * 128;
    KPAD[i+1] = OPAD[i];
  }

  const float* input  = (const float*)d_in[0];
  const float* latent = (const float*)d_in[1];
  auto Wp = [&](int i){ return (const float*)d_in[2 + 2*i]; };
  auto Bp = [&](int i){ return (const float*)d_in[3 + 2*i]; };

  const int Bn = in_sizes[1] / 256;
  const int Nn = in_sizes[0] / (3 * Bn);
  const int M  = Bn * Nn;                       // 16384

  float* out1 = (float*)d_out;                  // (B,1,N)
  float* out2 = out1 + M;                       // (B,N,1,3)
  float* out3 = out2 + (size_t)M * 3;           // input_con (B,N,259) fp32

  // ---- ws carve-up ----
  char* wsp = (char*)d_ws;
  u16 *WH[11], *WL[11];
  for (int i = 0; i < 11; ++i){
    const size_t sz = (size_t)OPAD[i] * KPAD[i] * 2;  // bytes per array
    WH[i] = (u16*)wsp; wsp += sz;
    WL[i] = (u16*)wsp; wsp += sz;
  }
  u16* x0 = (u16*)wsp;
  const long long psX0 = (long long)M * 288;
  wsp += (size_t)2 * psX0 * 2;

  const size_t used = (size_t)(wsp - (char*)d_ws);
  const size_t remain = (ws_size > used) ? (ws_size - used) : 0;
  const size_t perPoint = (size_t)2 * 5 * 1024 * 2;   // 20480 B/pt (2 bufs)
  long long pc = (long long)(remain / perPoint);
  pc &= ~63LL;
  int Pc = (int)((pc < (long long)M) ? pc : (long long)M);
  if (Pc < 64) Pc = 64;
  u16* bufA = (u16*)wsp;
  u16* bufB = bufA + (size_t)5 * Pc * 1024;

  // ---- prologue: input_con + x0 split, weight splits ----
  prep_input<<<M, 320, 0, stream>>>(input, latent, out3, x0, psX0, Nn);
  for (int i = 0; i < 11; ++i){
    const int total = OPAD[i] * KPAD[i];
    split_w<<<(total + 255)/256, 256, 0, stream>>>(
        Wp(i), WH[i], WL[i], COUT[i], CIN[i], KPAD[i], total);
  }

  // ---- layer chain (chunked over points if ws is small) ----
  for (int cm0 = 0; cm0 < M; cm0 += Pc){
    const int Mc = (M - cm0 < Pc) ? (M - cm0) : Pc;

    {
      dim3 g(Mc/64, OPAD[0]/128);
      fused_layer<2><<<g, 256, 0, stream>>>(
          x0 + (long long)cm0 * 288, psX0, 288,
          bufA, (long long)Pc * OPAD[0], OPAD[0],
          WH[0], WL[0], Bp(0), Wp(0), COUT[0], CIN[0]);
    }
    u16* src = bufA;
    u16* dst = bufB;
    for (int i = 1; i <= 10; ++i){
      dim3 g(Mc/64, OPAD[i]/128);
      fused_layer<5><<<g, 256, 0, stream>>>(
          src, (long long)Pc * KPAD[i], KPAD[i],
          dst, (long long)Pc * OPAD[i], OPAD[i],
          WH[i], WL[i], Bp(i), nullptr, COUT[i], 0);
      u16* t = src; src = dst; dst = t;
    }
    final_layer<<<Mc/4, 256, 0, stream>>>(
        src, (long long)Pc * KPAD[11], KPAD[11],
        Wp(11), Bp(11), out1, out2, CIN[11], cm0);
  }
}

// Round 3
// 2826.524 us; speedup vs baseline: 3.6176x; 1.1187x over previous
//
#include <hip/hip_runtime.h>
#include <math.h>

// ===========================================================================
// ImplicitMap fExtractor on MFMA (fp16 split scheme), round 3.
// State per point = 5 fp16 planes: [x_hi, x_lo, g1, g2, g3].
//   x carried as exact fp16 hi+lo pair -> 3-pass MFMA == fp32-accurate z.
//   g planes single-pass fp16.
// Round-3 changes (schedule/locality only, math identical):
//   * counted-vmcnt 2-buffer pipeline (raw s_barrier, loads span barriers,
//     issued one full iteration ahead)  [T3/T4]
//   * Pc capped at 8192 points so ping-pong state is L3-resident
//   * bijective XCD swizzle: each XCD owns a contiguous o-band (weight
//     slices stay in its private L2)  [T1]
//   * s_setprio(1) around the MFMA cluster  [T5]
// ===========================================================================

typedef unsigned short u16;
typedef _Float16 f16;
typedef f16   f16x8  __attribute__((ext_vector_type(8)));
typedef float f32x16 __attribute__((ext_vector_type(16)));

__device__ __forceinline__ u16   f2h(float x){ return __builtin_bit_cast(u16, (f16)x); }
__device__ __forceinline__ float h2f(u16 b){ return (float)__builtin_bit_cast(f16, b); }

__device__ __forceinline__ void glld16(const void* g, void* l){
  __builtin_amdgcn_global_load_lds(
      (const __attribute__((address_space(1))) unsigned*)g,
      (__attribute__((address_space(3))) unsigned*)l, 16, 0, 0);
}

template<int N> __device__ __forceinline__ void wait_vmcnt(){
  static_assert(N == 0 || N == 6 || N == 9, "unsupported vmcnt literal");
  if constexpr (N == 0) asm volatile("s_waitcnt vmcnt(0)" ::: "memory");
  if constexpr (N == 6) asm volatile("s_waitcnt vmcnt(6)" ::: "memory");
  if constexpr (N == 9) asm volatile("s_waitcnt vmcnt(9)" ::: "memory");
}

// NP = input planes staged: 2 for layer 1 (x hi/lo), 5 for mid layers.
template<int NP>
__global__ __launch_bounds__(256, 2)
void fused_layer(const u16* __restrict__ Sin, long long psIn, int kpad,
                 u16* __restrict__ Sout, long long psOut, int opitch,
                 const u16* __restrict__ Wh, const u16* __restrict__ Wl,
                 const float* __restrict__ bias, const float* __restrict__ Wfirst,
                 int cout, int cinFirst)
{
  constexpr bool FIRST = (NP == 2);
  constexpr int  S     = NP + 4;    // global_load_lds per wave per stage
  // K-outer-major: [buf][tile][kq(8-elem block)][row][8]; 16B cell per (kq,row)
  __shared__ u16 As[2][NP][4][64][8];
  __shared__ u16 Bs[2][2][4][128][8];

  // ---- bijective XCD swizzle: XCD x owns a contiguous role range -> a
  // contiguous o-band, so its private L2 caches only that weight slice.
  int bx = blockIdx.x, by = blockIdx.y;
  {
    const int nwg = gridDim.x * gridDim.y;
    const int d   = by * gridDim.x + bx;
    if ((nwg & 7) == 0){
      const int q = nwg >> 3;
      const int r = (d & 7) * q + (d >> 3);
      bx = r % gridDim.x;
      by = r / gridDim.x;
    }
  }

  const int tid   = threadIdx.x;
  const int w     = tid >> 6;     // wave id: stages kq-block w of every tile
  const int lane  = tid & 63;
  const int lrow  = lane & 31;
  const int lhalf = lane >> 5;
  const int mh    = w >> 1;       // wave's m-half (32 rows)
  const int oh    = w & 1;        // wave's o-half (64 cols)
  const int m0    = bx * 64;
  const int o0    = by * 128;

  f32x16 zinit = {};
  f32x16 accx[2];
  f32x16 accg[FIRST ? 1 : 3][2];
  accx[0] = zinit; accx[1] = zinit;
  if constexpr (!FIRST){
    #pragma unroll
    for (int j = 0; j < 3; ++j){ accg[j][0] = zinit; accg[j][1] = zinit; }
  }

  // per-lane global sources (lane -> LDS base + lane*16 by glld semantics)
  const u16* aSrc[NP];
  #pragma unroll
  for (int p = 0; p < NP; ++p)
    aSrc[p] = Sin + (long long)p * psIn + (long long)(m0 + lane) * kpad + w * 8;
  const u16* bSrc[2][2];
  #pragma unroll
  for (int h = 0; h < 2; ++h){
    const u16* Wx = h ? Wl : Wh;
    #pragma unroll
    for (int hf = 0; hf < 2; ++hf)
      bSrc[h][hf] = Wx + (long long)(o0 + hf*64 + lane) * kpad + w * 8;
  }

  auto stage = [&](int buf, int kElem){
    #pragma unroll
    for (int p = 0; p < NP; ++p)
      glld16(aSrc[p] + kElem, &As[buf][p][w][0][0]);
    #pragma unroll
    for (int h = 0; h < 2; ++h)
      #pragma unroll
      for (int hf = 0; hf < 2; ++hf)
        glld16(bSrc[h][hf] + kElem, &Bs[buf][h][w][hf*64][0]);
  };

  auto compute = [&](int buf){
    __builtin_amdgcn_s_setprio(1);
    #pragma unroll
    for (int s = 0; s < 2; ++s){
      const int kq = s*2 + lhalf;        // A/B frag: k = 8*(lane>>5)+e
      f16x8 a[NP];
      #pragma unroll
      for (int p = 0; p < NP; ++p)
        a[p] = *(const f16x8*)&As[buf][p][kq][mh*32 + lrow][0];
      #pragma unroll
      for (int f = 0; f < 2; ++f){
        const int oc = oh*64 + f*32 + lrow;
        f16x8 bh = *(const f16x8*)&Bs[buf][0][kq][oc][0];
        f16x8 bl = *(const f16x8*)&Bs[buf][1][kq][oc][0];
        // x plane: 3-pass split (xh*Wh + xl*Wh + xh*Wl), ~fp32 accurate
        accx[f] = __builtin_amdgcn_mfma_f32_32x32x16_f16(a[0], bh, accx[f], 0,0,0);
        accx[f] = __builtin_amdgcn_mfma_f32_32x32x16_f16(a[1], bh, accx[f], 0,0,0);
        accx[f] = __builtin_amdgcn_mfma_f32_32x32x16_f16(a[0], bl, accx[f], 0,0,0);
        if constexpr (!FIRST){
          #pragma unroll
          for (int j = 0; j < 3; ++j)   // g planes: single pass
            accg[j][f] = __builtin_amdgcn_mfma_f32_32x32x16_f16(a[2+j], bh, accg[j][f], 0,0,0);
        }
      }
    }
    __builtin_amdgcn_s_setprio(0);
  };

  // ---- counted-vmcnt double-buffered K loop ----
  const int nk = kpad >> 5;
  stage(0, 0);
  stage(1, 32);
  int cur = 0;
  for (int t = 0; t < nk - 1; ++t){
    wait_vmcnt<S>();                 // tile t landed (t+1 still in flight)
    __builtin_amdgcn_s_barrier();
    compute(cur);
    asm volatile("s_waitcnt lgkmcnt(0)" ::: "memory");  // my LDS reads returned
    __builtin_amdgcn_s_barrier();    // everyone done reading buf[cur]
    if (t + 2 < nk) stage(cur, (t + 2) * 32);
    cur ^= 1;
  }
  wait_vmcnt<0>();
  __builtin_amdgcn_s_barrier();
  compute(cur);

  // ---- epilogue: D layout col=lane&31, row=(r&3)+8*(r>>2)+4*(lane>>5) ----
  const int mb = m0 + mh*32;
  #pragma unroll
  for (int f = 0; f < 2; ++f){
    const int o = o0 + oh*64 + f*32 + lrow;
    const float bo = (o < cout) ? bias[o] : 0.f;
    float w0 = 0.f, w1 = 0.f, w2 = 0.f;
    if constexpr (FIRST){
      if (o < cout){
        w0 = Wfirst[(long long)o*cinFirst + 0];
        w1 = Wfirst[(long long)o*cinFirst + 1];
        w2 = Wfirst[(long long)o*cinFirst + 2];
      }
    }
    #pragma unroll
    for (int r = 0; r < 16; ++r){
      const int m = mb + (r & 3) + ((r >> 2) << 3) + (lhalf << 2);
      const float z    = accx[f][r] + bo;
      const float gate = 1.f / (1.f + expf(-100.f * z));
      const float sp   = fmaxf(z, 0.f) + 0.01f * log1pf(expf(-100.f * fabsf(z)));
      const long long idx = (long long)m * opitch + o;
      const u16 xh = f2h(sp);
      Sout[idx]          = xh;
      Sout[psOut + idx]  = f2h(sp - h2f(xh));
      if constexpr (FIRST){
        Sout[2*psOut + idx] = f2h(gate * w0);
        Sout[3*psOut + idx] = f2h(gate * w1);
        Sout[4*psOut + idx] = f2h(gate * w2);
      } else {
        Sout[2*psOut + idx] = f2h(gate * accg[0][f][r]);
        Sout[3*psOut + idx] = f2h(gate * accg[1][f][r]);
        Sout[4*psOut + idx] = f2h(gate * accg[2][f][r]);
      }
    }
  }
}

// Final 896->1: z (no act) -> out1; g = W@g (no gate) -> out2.
__global__ __launch_bounds__(256)
void final_layer(const u16* __restrict__ Sin, long long ps, int kpad,
                 const float* __restrict__ W, const float* __restrict__ bias,
                 float* __restrict__ out1, float* __restrict__ out2,
                 int cin, int mBase)
{
  const int lane = threadIdx.x & 63;
  const int wv   = threadIdx.x >> 6;
  const int m = blockIdx.x * 4 + wv;
  const u16* row = Sin + (long long)m * kpad;
  float s0=0.f, s1=0.f, s2=0.f, s3=0.f;
  for (int c = lane; c < cin; c += 64){
    const float w = W[c];
    s0 += (h2f(row[c]) + h2f(row[ps + c])) * w;
    s1 += h2f(row[2*ps + c]) * w;
    s2 += h2f(row[3*ps + c]) * w;
    s3 += h2f(row[4*ps + c]) * w;
  }
  #pragma unroll
  for (int off = 32; off > 0; off >>= 1){
    s0 += __shfl_xor(s0, off); s1 += __shfl_xor(s1, off);
    s2 += __shfl_xor(s2, off); s3 += __shfl_xor(s3, off);
  }
  if (lane == 0){
    out1[mBase + m] = s0 + bias[0];
    float* g = out2 + (long long)(mBase + m) * 3;
    g[0] = s1; g[1] = s2; g[2] = s3;
  }
}

// out3 = input_con (fp32), plus padded fp16 hi/lo copy for the layer-1 GEMM.
__global__ void prep_input(const float* __restrict__ input,
                           const float* __restrict__ latent,
                           float* __restrict__ out3,
                           u16* __restrict__ x0, long long psX0, int N)
{
  const int m = blockIdx.x;
  const int b = m / N;
  const int c = threadIdx.x;
  if (c >= 288) return;
  float v = 0.f;
  if (c < 3) v = input[(long long)m*3 + c];
  else if (c < 259) v = latent[(long long)b*256 + (c - 3)];
  if (c < 259) out3[(long long)m*259 + c] = v;
  const u16 h = f2h(v);
  x0[(long long)m*288 + c]        = h;
  x0[psX0 + (long long)m*288 + c] = f2h(v - h2f(h));
}

// fp32 W -> zero-padded fp16 hi/lo.
__global__ void split_w(const float* __restrict__ W, u16* __restrict__ wh,
                        u16* __restrict__ wl, int cout, int cin, int kpad, int total)
{
  const int idx = blockIdx.x * 256 + threadIdx.x;
  if (idx >= total) return;
  const int o = idx / kpad, c = idx % kpad;
  const float v = (o < cout && c < cin) ? W[(long long)o*cin + c] : 0.f;
  const u16 h = f2h(v);
  wh[idx] = h;
  wl[idx] = f2h(v - h2f(h));
}

extern "C" void kernel_launch(void* const* d_in, const int* in_sizes, int n_in,
                              void* d_out, int out_size, void* d_ws, size_t ws_size,
                              hipStream_t stream)
{
  static const int CIN [12] = {259,515,512,512,576,576,768,768,768,960,960,896};
  static const int COUT[12] = {515,512,512,576,576,768,768,768,960,960,896,1};
  int OPAD[11], KPAD[12];
  KPAD[0] = 288;
  for (int i = 0; i < 11; ++i){
    OPAD[i] = ((COUT[i] + 127) / 128) * 128;
    KPAD[i+1] = OPAD[i];
  }

  const float* input  = (const float*)d_in[0];
  const float* latent = (const float*)d_in[1];
  auto Wp = [&](int i){ return (const float*)d_in[2 + 2*i]; };
  auto Bp = [&](int i){ return (const float*)d_in[3 + 2*i]; };

  const int Bn = in_sizes[1] / 256;
  const int Nn = in_sizes[0] / (3 * Bn);
  const int M  = Bn * Nn;                       // 16384

  float* out1 = (float*)d_out;                  // (B,1,N)
  float* out2 = out1 + M;                       // (B,N,1,3)
  float* out3 = out2 + (size_t)M * 3;           // input_con (B,N,259) fp32

  // ---- ws carve-up ----
  char* wsp = (char*)d_ws;
  u16 *WH[11], *WL[11];
  for (int i = 0; i < 11; ++i){
    const size_t sz = (size_t)OPAD[i] * KPAD[i] * 2;  // bytes per array
    WH[i] = (u16*)wsp; wsp += sz;
    WL[i] = (u16*)wsp; wsp += sz;
  }
  u16* x0 = (u16*)wsp;
  const long long psX0 = (long long)M * 288;
  wsp += (size_t)2 * psX0 * 2;

  const size_t used = (size_t)(wsp - (char*)d_ws);
  const size_t remain = (ws_size > used) ? (ws_size - used) : 0;
  const size_t perPoint = (size_t)2 * 5 * 1024 * 2;   // 20480 B/pt (2 bufs)
  long long pc = (long long)(remain / perPoint);
  pc &= ~63LL;
  // Cap at 8192 points: ping-pong state (~168 MB) stays L3-resident.
  int Pc = (int)((pc < 8192LL) ? pc : 8192LL);
  if (Pc > M) Pc = M;
  if (Pc < 64) Pc = 64;
  u16* bufA = (u16*)wsp;
  u16* bufB = bufA + (size_t)5 * Pc * 1024;

  // ---- prologue: input_con + x0 split, weight splits ----
  prep_input<<<M, 320, 0, stream>>>(input, latent, out3, x0, psX0, Nn);
  for (int i = 0; i < 11; ++i){
    const int total = OPAD[i] * KPAD[i];
    split_w<<<(total + 255)/256, 256, 0, stream>>>(
        Wp(i), WH[i], WL[i], COUT[i], CIN[i], KPAD[i], total);
  }

  // ---- layer chain (chunked over points; chunks are L3-resident) ----
  for (int cm0 = 0; cm0 < M; cm0 += Pc){
    const int Mc = (M - cm0 < Pc) ? (M - cm0) : Pc;

    {
      dim3 g(Mc/64, OPAD[0]/128);
      fused_layer<2><<<g, 256, 0, stream>>>(
          x0 + (long long)cm0 * 288, psX0, 288,
          bufA, (long long)Pc * OPAD[0], OPAD[0],
          WH[0], WL[0], Bp(0), Wp(0), COUT[0], CIN[0]);
    }
    u16* src = bufA;
    u16* dst = bufB;
    for (int i = 1; i <= 10; ++i){
      dim3 g(Mc/64, OPAD[i]/128);
      fused_layer<5><<<g, 256, 0, stream>>>(
          src, (long long)Pc * KPAD[i], KPAD[i],
          dst, (long long)Pc * OPAD[i], OPAD[i],
          WH[i], WL[i], Bp(i), nullptr, COUT[i], 0);
      u16* t = src; src = dst; dst = t;
    }
    final_layer<<<Mc/4, 256, 0, stream>>>(
        src, (long long)Pc * KPAD[11], KPAD[11],
        Wp(11), Bp(11), out1, out2, CIN[11], cm0);
  }
}

// Round 4
// 2569.294 us; speedup vs baseline: 3.9797x; 1.1001x over previous
//
#include <hip/hip_runtime.h>
#include <math.h>

// ===========================================================================
// ImplicitMap fExtractor on MFMA (fp16 split scheme), round 4.
// State per point = 5 fp16 planes: [x_hi, x_lo, g1, g2, g3].
//   x carried as exact fp16 hi+lo pair -> 3-pass MFMA == fp32-accurate z.
//   g planes single-pass fp16.
// Round-4 change (mapping only, math identical to round 3):
//   * XCD swizzle INVERTED: each XCD now owns a contiguous M-BAND with the
//     o-tile index varying FASTEST. The ~64 co-resident blocks per XCD then
//     cover all o-columns of a few adjacent m-tiles, so each A (state) line
//     is pulled across the fabric once per XCD L2 and reused by every
//     o-column, instead of being streamed 6-8x (once per o-column).
//     Weights are re-fetched per XCD instead (~38 MB total -- trivial).
// ===========================================================================

typedef unsigned short u16;
typedef _Float16 f16;
typedef f16   f16x8  __attribute__((ext_vector_type(8)));
typedef float f32x16 __attribute__((ext_vector_type(16)));

__device__ __forceinline__ u16   f2h(float x){ return __builtin_bit_cast(u16, (f16)x); }
__device__ __forceinline__ float h2f(u16 b){ return (float)__builtin_bit_cast(f16, b); }

__device__ __forceinline__ void glld16(const void* g, void* l){
  __builtin_amdgcn_global_load_lds(
      (const __attribute__((address_space(1))) unsigned*)g,
      (__attribute__((address_space(3))) unsigned*)l, 16, 0, 0);
}

template<int N> __device__ __forceinline__ void wait_vmcnt(){
  static_assert(N == 0 || N == 6 || N == 9, "unsupported vmcnt literal");
  if constexpr (N == 0) asm volatile("s_waitcnt vmcnt(0)" ::: "memory");
  if constexpr (N == 6) asm volatile("s_waitcnt vmcnt(6)" ::: "memory");
  if constexpr (N == 9) asm volatile("s_waitcnt vmcnt(9)" ::: "memory");
}

// NP = input planes staged: 2 for layer 1 (x hi/lo), 5 for mid layers.
template<int NP>
__global__ __launch_bounds__(256, 2)
void fused_layer(const u16* __restrict__ Sin, long long psIn, int kpad,
                 u16* __restrict__ Sout, long long psOut, int opitch,
                 const u16* __restrict__ Wh, const u16* __restrict__ Wl,
                 const float* __restrict__ bias, const float* __restrict__ Wfirst,
                 int cout, int cinFirst)
{
  constexpr bool FIRST = (NP == 2);
  constexpr int  S     = NP + 4;    // global_load_lds per wave per stage
  // K-outer-major: [buf][tile][kq(8-elem block)][row][8]; 16B cell per (kq,row)
  __shared__ u16 As[2][NP][4][64][8];
  __shared__ u16 Bs[2][2][4][128][8];

  // ---- XCD swizzle: XCD x gets a contiguous t-range; within it, the o-tile
  // index (by) varies fastest -> co-resident blocks on one XCD cover all
  // o-columns of adjacent m-tiles -> A stripes hit that XCD's L2.
  int bx = blockIdx.x, by = blockIdx.y;
  {
    const int gx = gridDim.x, gy = gridDim.y;
    const int nwg = gx * gy;
    const int d   = by * gx + bx;        // hw dispatch order (x fastest)
    if ((nwg & 7) == 0){
      const int q = nwg >> 3;
      const int t = (d & 7) * q + (d >> 3);
      by = t % gy;                       // o fastest
      bx = t / gy;                       // contiguous m-band per XCD
    }
  }

  const int tid   = threadIdx.x;
  const int w     = tid >> 6;     // wave id: stages kq-block w of every tile
  const int lane  = tid & 63;
  const int lrow  = lane & 31;
  const int lhalf = lane >> 5;
  const int mh    = w >> 1;       // wave's m-half (32 rows)
  const int oh    = w & 1;        // wave's o-half (64 cols)
  const int m0    = bx * 64;
  const int o0    = by * 128;

  f32x16 zinit = {};
  f32x16 accx[2];
  f32x16 accg[FIRST ? 1 : 3][2];
  accx[0] = zinit; accx[1] = zinit;
  if constexpr (!FIRST){
    #pragma unroll
    for (int j = 0; j < 3; ++j){ accg[j][0] = zinit; accg[j][1] = zinit; }
  }

  // per-lane global sources (lane -> LDS base + lane*16 by glld semantics)
  const u16* aSrc[NP];
  #pragma unroll
  for (int p = 0; p < NP; ++p)
    aSrc[p] = Sin + (long long)p * psIn + (long long)(m0 + lane) * kpad + w * 8;
  const u16* bSrc[2][2];
  #pragma unroll
  for (int h = 0; h < 2; ++h){
    const u16* Wx = h ? Wl : Wh;
    #pragma unroll
    for (int hf = 0; hf < 2; ++hf)
      bSrc[h][hf] = Wx + (long long)(o0 + hf*64 + lane) * kpad + w * 8;
  }

  auto stage = [&](int buf, int kElem){
    #pragma unroll
    for (int p = 0; p < NP; ++p)
      glld16(aSrc[p] + kElem, &As[buf][p][w][0][0]);
    #pragma unroll
    for (int h = 0; h < 2; ++h)
      #pragma unroll
      for (int hf = 0; hf < 2; ++hf)
        glld16(bSrc[h][hf] + kElem, &Bs[buf][h][w][hf*64][0]);
  };

  auto compute = [&](int buf){
    __builtin_amdgcn_s_setprio(1);
    #pragma unroll
    for (int s = 0; s < 2; ++s){
      const int kq = s*2 + lhalf;        // A/B frag: k = 8*(lane>>5)+e
      f16x8 a[NP];
      #pragma unroll
      for (int p = 0; p < NP; ++p)
        a[p] = *(const f16x8*)&As[buf][p][kq][mh*32 + lrow][0];
      #pragma unroll
      for (int f = 0; f < 2; ++f){
        const int oc = oh*64 + f*32 + lrow;
        f16x8 bh = *(const f16x8*)&Bs[buf][0][kq][oc][0];
        f16x8 bl = *(const f16x8*)&Bs[buf][1][kq][oc][0];
        // x plane: 3-pass split (xh*Wh + xl*Wh + xh*Wl), ~fp32 accurate
        accx[f] = __builtin_amdgcn_mfma_f32_32x32x16_f16(a[0], bh, accx[f], 0,0,0);
        accx[f] = __builtin_amdgcn_mfma_f32_32x32x16_f16(a[1], bh, accx[f], 0,0,0);
        accx[f] = __builtin_amdgcn_mfma_f32_32x32x16_f16(a[0], bl, accx[f], 0,0,0);
        if constexpr (!FIRST){
          #pragma unroll
          for (int j = 0; j < 3; ++j)   // g planes: single pass
            accg[j][f] = __builtin_amdgcn_mfma_f32_32x32x16_f16(a[2+j], bh, accg[j][f], 0,0,0);
        }
      }
    }
    __builtin_amdgcn_s_setprio(0);
  };

  // ---- counted-vmcnt double-buffered K loop ----
  const int nk = kpad >> 5;
  stage(0, 0);
  stage(1, 32);
  int cur = 0;
  for (int t = 0; t < nk - 1; ++t){
    wait_vmcnt<S>();                 // tile t landed (t+1 still in flight)
    __builtin_amdgcn_s_barrier();
    compute(cur);
    asm volatile("s_waitcnt lgkmcnt(0)" ::: "memory");  // my LDS reads returned
    __builtin_amdgcn_s_barrier();    // everyone done reading buf[cur]
    if (t + 2 < nk) stage(cur, (t + 2) * 32);
    cur ^= 1;
  }
  wait_vmcnt<0>();
  __builtin_amdgcn_s_barrier();
  compute(cur);

  // ---- epilogue: D layout col=lane&31, row=(r&3)+8*(r>>2)+4*(lane>>5) ----
  const int mb = m0 + mh*32;
  #pragma unroll
  for (int f = 0; f < 2; ++f){
    const int o = o0 + oh*64 + f*32 + lrow;
    const float bo = (o < cout) ? bias[o] : 0.f;
    float w0 = 0.f, w1 = 0.f, w2 = 0.f;
    if constexpr (FIRST){
      if (o < cout){
        w0 = Wfirst[(long long)o*cinFirst + 0];
        w1 = Wfirst[(long long)o*cinFirst + 1];
        w2 = Wfirst[(long long)o*cinFirst + 2];
      }
    }
    #pragma unroll
    for (int r = 0; r < 16; ++r){
      const int m = mb + (r & 3) + ((r >> 2) << 3) + (lhalf << 2);
      const float z    = accx[f][r] + bo;
      const float gate = 1.f / (1.f + expf(-100.f * z));
      const float sp   = fmaxf(z, 0.f) + 0.01f * log1pf(expf(-100.f * fabsf(z)));
      const long long idx = (long long)m * opitch + o;
      const u16 xh = f2h(sp);
      Sout[idx]          = xh;
      Sout[psOut + idx]  = f2h(sp - h2f(xh));
      if constexpr (FIRST){
        Sout[2*psOut + idx] = f2h(gate * w0);
        Sout[3*psOut + idx] = f2h(gate * w1);
        Sout[4*psOut + idx] = f2h(gate * w2);
      } else {
        Sout[2*psOut + idx] = f2h(gate * accg[0][f][r]);
        Sout[3*psOut + idx] = f2h(gate * accg[1][f][r]);
        Sout[4*psOut + idx] = f2h(gate * accg[2][f][r]);
      }
    }
  }
}

// Final 896->1: z (no act) -> out1; g = W@g (no gate) -> out2.
__global__ __launch_bounds__(256)
void final_layer(const u16* __restrict__ Sin, long long ps, int kpad,
                 const float* __restrict__ W, const float* __restrict__ bias,
                 float* __restrict__ out1, float* __restrict__ out2,
                 int cin, int mBase)
{
  const int lane = threadIdx.x & 63;
  const int wv   = threadIdx.x >> 6;
  const int m = blockIdx.x * 4 + wv;
  const u16* row = Sin + (long long)m * kpad;
  float s0=0.f, s1=0.f, s2=0.f, s3=0.f;
  for (int c = lane; c < cin; c += 64){
    const float w = W[c];
    s0 += (h2f(row[c]) + h2f(row[ps + c])) * w;
    s1 += h2f(row[2*ps + c]) * w;
    s2 += h2f(row[3*ps + c]) * w;
    s3 += h2f(row[4*ps + c]) * w;
  }
  #pragma unroll
  for (int off = 32; off > 0; off >>= 1){
    s0 += __shfl_xor(s0, off); s1 += __shfl_xor(s1, off);
    s2 += __shfl_xor(s2, off); s3 += __shfl_xor(s3, off);
  }
  if (lane == 0){
    out1[mBase + m] = s0 + bias[0];
    float* g = out2 + (long long)(mBase + m) * 3;
    g[0] = s1; g[1] = s2; g[2] = s3;
  }
}

// out3 = input_con (fp32), plus padded fp16 hi/lo copy for the layer-1 GEMM.
__global__ void prep_input(const float* __restrict__ input,
                           const float* __restrict__ latent,
                           float* __restrict__ out3,
                           u16* __restrict__ x0, long long psX0, int N)
{
  const int m = blockIdx.x;
  const int b = m / N;
  const int c = threadIdx.x;
  if (c >= 288) return;
  float v = 0.f;
  if (c < 3) v = input[(long long)m*3 + c];
  else if (c < 259) v = latent[(long long)b*256 + (c - 3)];
  if (c < 259) out3[(long long)m*259 + c] = v;
  const u16 h = f2h(v);
  x0[(long long)m*288 + c]        = h;
  x0[psX0 + (long long)m*288 + c] = f2h(v - h2f(h));
}

// fp32 W -> zero-padded fp16 hi/lo.
__global__ void split_w(const float* __restrict__ W, u16* __restrict__ wh,
                        u16* __restrict__ wl, int cout, int cin, int kpad, int total)
{
  const int idx = blockIdx.x * 256 + threadIdx.x;
  if (idx >= total) return;
  const int o = idx / kpad, c = idx % kpad;
  const float v = (o < cout && c < cin) ? W[(long long)o*cin + c] : 0.f;
  const u16 h = f2h(v);
  wh[idx] = h;
  wl[idx] = f2h(v - h2f(h));
}

extern "C" void kernel_launch(void* const* d_in, const int* in_sizes, int n_in,
                              void* d_out, int out_size, void* d_ws, size_t ws_size,
                              hipStream_t stream)
{
  static const int CIN [12] = {259,515,512,512,576,576,768,768,768,960,960,896};
  static const int COUT[12] = {515,512,512,576,576,768,768,768,960,960,896,1};
  int OPAD[11], KPAD[12];
  KPAD[0] = 288;
  for (int i = 0; i < 11; ++i){
    OPAD[i] = ((COUT[i] + 127) / 128) * 128;
    KPAD[i+1] = OPAD[i];
  }

  const float* input  = (const float*)d_in[0];
  const float* latent = (const float*)d_in[1];
  auto Wp = [&](int i){ return (const float*)d_in[2 + 2*i]; };
  auto Bp = [&](int i){ return (const float*)d_in[3 + 2*i]; };

  const int Bn = in_sizes[1] / 256;
  const int Nn = in_sizes[0] / (3 * Bn);
  const int M  = Bn * Nn;                       // 16384

  float* out1 = (float*)d_out;                  // (B,1,N)
  float* out2 = out1 + M;                       // (B,N,1,3)
  float* out3 = out2 + (size_t)M * 3;           // input_con (B,N,259) fp32

  // ---- ws carve-up ----
  char* wsp = (char*)d_ws;
  u16 *WH[11], *WL[11];
  for (int i = 0; i < 11; ++i){
    const size_t sz = (size_t)OPAD[i] * KPAD[i] * 2;  // bytes per array
    WH[i] = (u16*)wsp; wsp += sz;
    WL[i] = (u16*)wsp; wsp += sz;
  }
  u16* x0 = (u16*)wsp;
  const long long psX0 = (long long)M * 288;
  wsp += (size_t)2 * psX0 * 2;

  const size_t used = (size_t)(wsp - (char*)d_ws);
  const size_t remain = (ws_size > used) ? (ws_size - used) : 0;
  const size_t perPoint = (size_t)2 * 5 * 1024 * 2;   // 20480 B/pt (2 bufs)
  long long pc = (long long)(remain / perPoint);
  pc &= ~63LL;
  // Cap at 8192 points: ping-pong state (~126 MB) stays L3-resident.
  int Pc = (int)((pc < 8192LL) ? pc : 8192LL);
  if (Pc > M) Pc = M;
  if (Pc < 64) Pc = 64;
  u16* bufA = (u16*)wsp;
  u16* bufB = bufA + (size_t)5 * Pc * 1024;

  // ---- prologue: input_con + x0 split, weight splits ----
  prep_input<<<M, 320, 0, stream>>>(input, latent, out3, x0, psX0, Nn);
  for (int i = 0; i < 11; ++i){
    const int total = OPAD[i] * KPAD[i];
    split_w<<<(total + 255)/256, 256, 0, stream>>>(
        Wp(i), WH[i], WL[i], COUT[i], CIN[i], KPAD[i], total);
  }

  // ---- layer chain (chunked over points; chunks are L3-resident) ----
  for (int cm0 = 0; cm0 < M; cm0 += Pc){
    const int Mc = (M - cm0 < Pc) ? (M - cm0) : Pc;

    {
      dim3 g(Mc/64, OPAD[0]/128);
      fused_layer<2><<<g, 256, 0, stream>>>(
          x0 + (long long)cm0 * 288, psX0, 288,
          bufA, (long long)Pc * OPAD[0], OPAD[0],
          WH[0], WL[0], Bp(0), Wp(0), COUT[0], CIN[0]);
    }
    u16* src = bufA;
    u16* dst = bufB;
    for (int i = 1; i <= 10; ++i){
      dim3 g(Mc/64, OPAD[i]/128);
      fused_layer<5><<<g, 256, 0, stream>>>(
          src, (long long)Pc * KPAD[i], KPAD[i],
          dst, (long long)Pc * OPAD[i], OPAD[i],
          WH[i], WL[i], Bp(i), nullptr, COUT[i], 0);
      u16* t = src; src = dst; dst = t;
    }
    final_layer<<<Mc/4, 256, 0, stream>>>(
        src, (long long)Pc * KPAD[11], KPAD[11],
        Wp(11), Bp(11), out1, out2, CIN[11], cm0);
  }
}